// Round 18
// baseline (116.795 us; speedup 1.0000x reference)
//
#include <hip/hip_runtime.h>
#include <math.h>

#define LL    4096
#define CDIM  96
#define DIN   192
#define NST   16
#define XE    38   // dt_rank(6) + 2*16

typedef __attribute__((ext_vector_type(8))) short v8s;
typedef __attribute__((ext_vector_type(4))) float v4f;
typedef unsigned short ushort_t;
typedef unsigned int uint_t;

#if __has_builtin(__builtin_amdgcn_exp2f)
__device__ __forceinline__ float fexp2(float x) { return __builtin_amdgcn_exp2f(x); }
#else
__device__ __forceinline__ float fexp2(float x) { return exp2f(x); }
#endif
#if __has_builtin(__builtin_amdgcn_logf)
__device__ __forceinline__ float flog2(float x) { return __builtin_amdgcn_logf(x); }
#else
__device__ __forceinline__ float flog2(float x) { return __log2f(x); }
#endif

__device__ __forceinline__ float siluf(float x) {
    return x * __builtin_amdgcn_rcpf(1.f + fexp2(-1.44269504f * x));
}
__device__ __forceinline__ ushort_t f2bf(float f) {
    uint_t u = __builtin_bit_cast(uint_t, f);
    return (ushort_t)((u + 0x7fffu + ((u >> 16) & 1u)) >> 16);
}
__device__ __forceinline__ float bf2f(ushort_t u) {
    return __builtin_bit_cast(float, (uint_t)u << 16);
}

// ---------------- Kernel 1: weight prep (LDS-staged merge) + cvt + x pad, ONE launch
__global__ __launch_bounds__(256) void k_prep(const float* __restrict__ proj_w,
                                              const float* __restrict__ dconv_w,
                                              const float* __restrict__ in_proj_w,
                                              const float* __restrict__ out_proj_w,
                                              const float* __restrict__ x_proj_w,
                                              const float* __restrict__ x,
                                              ushort_t* __restrict__ Wbf,
                                              ushort_t* __restrict__ Wibf,
                                              ushort_t* __restrict__ Wobf,
                                              ushort_t* __restrict__ Wxbf,
                                              ushort_t* __restrict__ xT) {
    __shared__ float s_dc[1728];
    int bid = blockIdx.x;
    if (bid < 96) {                       // merge proj into dconv, block per o
        int o = bid;
        for (int i = threadIdx.x; i < 1728; i += 256)
            s_dc[i] = dconv_w[o * 1728 + i];     // contiguous (i = j*9+k)
        __syncthreads();
        for (int u2 = threadIdx.x; u2 < 864; u2 += 256) {
            int c = u2 % 96, k = u2 / 96;
            float s = 0.f;
            for (int j2 = 0; j2 < 192; ++j2)
                s = fmaf(s_dc[j2 * 9 + k], proj_w[j2 * 96 + c], s);
            Wbf[(k * 96 + o) * 96 + c] = f2bf(s);
        }
        return;
    }
    if (bid < 348) {                      // weight cvt
        int i = (bid - 96) * 256 + threadIdx.x;
        if (i < 36864) { Wibf[i] = f2bf(in_proj_w[i]); return; }
        i -= 36864;
        if (i < 18432) { Wobf[i] = f2bf(out_proj_w[i]); return; }
        i -= 18432;
        if (i < 9216) {
            int e = i / 192;
            Wxbf[i] = (e < XE) ? f2bf(x_proj_w[i]) : (ushort_t)0;
        }
        return;
    }
    // xpad: x (B,96,64,64) f32 -> xT[b][66][68][96] bf16, zero halo
    int bid2 = bid - 348;
    int yy = bid2 % 66;
    int b  = bid2 / 66;
    int yv = yy - 1;
    for (int i = threadIdx.x; i < 68 * 12; i += 256) {
        int xx = i % 68, cig = i / 68;
        int xv = xx - 1;
        ushort_t u[8];
        if (yv >= 0 && yv < 64 && xv >= 0 && xv < 64) {
            const float* sp = x + ((size_t)(b * 96 + cig * 8)) * LL + yv * 64 + xv;
#pragma unroll
            for (int j = 0; j < 8; ++j) u[j] = f2bf(sp[j * LL]);
        } else {
#pragma unroll
            for (int j = 0; j < 8; ++j) u[j] = 0;
        }
        uint4 pk;
        pk.x = u[0] | ((uint_t)u[1] << 16); pk.y = u[2] | ((uint_t)u[3] << 16);
        pk.z = u[4] | ((uint_t)u[5] << 16); pk.w = u[6] | ((uint_t)u[7] << 16);
        *(uint4*)(xT + (((size_t)b * 66 + yy) * 68 + xx) * 96 + cig * 8) = pk;
    }
}

// ---------------- Kernel 2: FUSED 3x3-conv + in_proj via MFMA, 16-l tiles (1024 blocks)
__global__ __launch_bounds__(384, 6) void k_convin(const ushort_t* __restrict__ xT,
                                                   const ushort_t* __restrict__ Wbf,
                                                   const ushort_t* __restrict__ Wibf,
                                                   ushort_t* __restrict__ xzb) {
    __shared__ ushort_t s_xt[3 * 18 * 100];   // 10.8 KB
    __shared__ ushort_t s_seq[16 * 104];      // 3.3 KB
    int tid = threadIdx.x;
    int w = tid >> 6, l = tid & 63;
    int n = l & 15, g = l >> 4;
    int blk = blockIdx.x;
    int b = blk >> 8, rem = blk & 255;
    int y = rem >> 2, q = rem & 3;            // l-tile = q*16
    // ---- stage input tile: rows y..y+2, cols q*16 .. q*16+17 (18), all 96 ci
    {
        const ushort_t* gsrc = xT + ((size_t)(b * 66 + y) * 68 + q * 16) * 96;
        for (int idx = tid; idx < 648; idx += 384) {     // 648 = 3*18*12 uint4
            int r = idx / 216, rm = idx % 216;
            int col = rm / 12, ci8 = rm % 12;
            uint4 v = *(const uint4*)(gsrc + ((size_t)r * 68 + col) * 96 + ci8 * 8);
            *(uint4*)&s_xt[(r * 18 + col) * 100 + ci8 * 8] = v;
        }
    }
    __syncthreads();
    // ---- conv 3x3 from LDS: wave w -> co tile w*16, 16 l x 16 co
    int co0 = w * 16;
    v4f acc0 = {0.f, 0.f, 0.f, 0.f};
    const ushort_t* xbl = &s_xt[n * 100 + g * 8];
    const ushort_t* aw = Wbf + ((size_t)co0 + n) * 96 + g * 8;
#pragma unroll
    for (int tap = 0; tap < 9; ++tap) {
        int dy = tap / 3, dx = tap % 3;
        const ushort_t* bp = xbl + (dy * 18 + dx) * 100;
        const ushort_t* ap = aw + (size_t)tap * 9216;
#pragma unroll
        for (int kk = 0; kk < 3; ++kk) {
            v8s bf = *(const v8s*)(bp + kk * 32);
            v8s a0 = *(const v8s*)(ap + kk * 32);
            acc0 = __builtin_amdgcn_mfma_f32_16x16x32_bf16(a0, bf, acc0, 0, 0, 0);
        }
    }
    {
        ushort_t* sp = s_seq + n * 104 + co0 + g * 4;
        ushort4 p0;
        p0.x = f2bf(acc0[0]); p0.y = f2bf(acc0[1]); p0.z = f2bf(acc0[2]); p0.w = f2bf(acc0[3]);
        *(ushort4*)sp = p0;
    }
    __syncthreads();
    // ---- in_proj: wave w handles e in [w*64, w*64+64)
    int coh = w * 64;
    v4f acc[4];
#pragma unroll
    for (int mt = 0; mt < 4; ++mt) acc[mt] = (v4f){0.f, 0.f, 0.f, 0.f};
    const ushort_t* ap2 = Wibf + ((size_t)coh + n) * 96 + g * 8;
    const ushort_t* bp2 = s_seq + n * 104 + g * 8;
#pragma unroll
    for (int kk = 0; kk < 3; ++kk) {
        v8s bf = *(const v8s*)(bp2 + kk * 32);
#pragma unroll
        for (int mt = 0; mt < 4; ++mt) {
            v8s af = *(const v8s*)(ap2 + mt * 16 * 96 + kk * 32);
            acc[mt] = __builtin_amdgcn_mfma_f32_16x16x32_bf16(af, bf, acc[mt], 0, 0, 0);
        }
    }
    int l0g = y * 64 + q * 16;
    ushort_t* ob = xzb + (size_t)b * 384 * LL + l0g + n;
#pragma unroll
    for (int mt = 0; mt < 4; ++mt) {
        int e = coh + mt * 16 + g * 4;
#pragma unroll
        for (int r = 0; r < 4; ++r)
            ob[(size_t)(e + r) * LL] = f2bf(acc[mt][r]);
    }
}

// ---------------- Kernel 3: FUSED conv1d+SiLU + x_proj, 6 balanced MFMA waves
__global__ __launch_bounds__(384, 2) void k_convxp(const ushort_t* __restrict__ xzb,
                                                   const float* __restrict__ c1w,
                                                   const float* __restrict__ c1b,
                                                   const ushort_t* __restrict__ Wxbf,
                                                   ushort_t* __restrict__ xcR,
                                                   float* __restrict__ dtT,
                                                   float* __restrict__ BtP,
                                                   float* __restrict__ CtP) {
    __shared__ ushort_t s_xc[32][200];
    int tid = threadIdx.x;
    int b = blockIdx.y;
    int l0 = blockIdx.x * 32;
    if (tid < 192) {
        int d = tid;
        const ushort_t* xin = xzb + (size_t)(b * 384 + d) * LL;
        float e[35];
        if (l0 > 0) {
            v8s pv = *(const v8s*)(xin + l0 - 8);
            e[0] = bf2f((ushort_t)pv[5]); e[1] = bf2f((ushort_t)pv[6]); e[2] = bf2f((ushort_t)pv[7]);
        } else {
            e[0] = e[1] = e[2] = 0.f;
        }
#pragma unroll
        for (int q = 0; q < 4; ++q) {
            v8s cv = *(const v8s*)(xin + l0 + q * 8);
#pragma unroll
            for (int j = 0; j < 8; ++j) e[3 + q * 8 + j] = bf2f((ushort_t)cv[j]);
        }
        float w0 = c1w[d * 4], w1 = c1w[d * 4 + 1], w2 = c1w[d * 4 + 2], w3 = c1w[d * 4 + 3];
        float bb = c1b[d];
        ushort_t* xr = xcR + (size_t)(b * 192 + d) * LL + l0;
#pragma unroll
        for (int q = 0; q < 4; ++q) {
            v8s ov;
#pragma unroll
            for (int j = 0; j < 8; ++j) {
                int i = q * 8 + j;
                float s = bb + w0 * e[i] + w1 * e[i + 1] + w2 * e[i + 2] + w3 * e[i + 3];
                ushort_t uv = f2bf(siluf(s));
                ov[j] = (short)uv;
                s_xc[i][d] = uv;
            }
            *(v8s*)(xr + q * 8) = ov;
        }
    }
    __syncthreads();
    // 6 waves: wave w -> (t-half th = w&1, m-tile m = w>>1); 6 MFMAs each
    int w = tid >> 6, l = tid & 63;
    int n = l & 15, g = l >> 4;
    int th = w & 1, m = w >> 1;
    int lt = th * 16;
    int t = l0 + lt + n;
    const ushort_t* ap = Wxbf + ((size_t)(m * 16) + n) * 192 + g * 8;
    float* dtb = dtT + (size_t)b * 6 * LL + t;
    float* Bb  = BtP + ((size_t)b * LL + t) * 16;
    float* Cb  = CtP + ((size_t)b * LL + t) * 16;
    v4f acc = {0.f, 0.f, 0.f, 0.f};
#pragma unroll
    for (int kk = 0; kk < 6; ++kk) {
        v8s bf = *(const v8s*)&s_xc[lt + n][g * 8 + kk * 32];
        v8s af = *(const v8s*)(ap + kk * 32);
        acc = __builtin_amdgcn_mfma_f32_16x16x32_bf16(af, bf, acc, 0, 0, 0);
    }
#pragma unroll
    for (int r = 0; r < 4; ++r) {
        int e = m * 16 + g * 4 + r;
        float v = acc[r];
        if (e < 6)       dtb[(size_t)e * LL] = v;
        else if (e < 22) Bb[e - 6] = v;
        else if (e < 38) Cb[e - 22] = v;
    }
}

// ---------------- Kernel 4: selective scan (fused dt_proj+softplus) -> yg[d][t] bf16
__global__ __launch_bounds__(512, 6) void k_scan(const float* __restrict__ dtT,
                                                 const float* __restrict__ dtw,
                                                 const float* __restrict__ dtpb,
                                                 const ushort_t* __restrict__ xcR,
                                                 const float* __restrict__ BtP,
                                                 const float* __restrict__ CtP,
                                                 const float* __restrict__ A_log,
                                                 const float* __restrict__ Dp,
                                                 ushort_t* __restrict__ xzb) {
    __shared__ float s_d[32 * 132];       // chunk c at c*132 (+4 pad)
    __shared__ float s_u[32 * 132];
    __shared__ float s_a[32][17];
    __shared__ float s_h[32][17];
    int tid = threadIdx.x;
    int n = tid & 15, cg = tid >> 4;      // 32 chunks x 16 states
    int bd = blockIdx.x;
    int d = bd % DIN, b = bd / DIN;
    const ushort_t* urow = xcR + (size_t)(b * 192 + d) * LL;
    const ushort_t* zrow = xzb + (size_t)(b * 384 + DIN + d) * LL;
    ushort_t* ygr = xzb + (size_t)(b * 384 + d) * LL;    // overwrites dead xin row
    float A2 = -__expf(A_log[d * NST + n]) * 1.44269504f;   // for fexp2
    float Dd = Dp[d];

    // ---- staging: u from xcR bf16; delta = softplus(dt_proj) in-kernel
    {
        int t8 = tid * 8;
        int li = ((t8 >> 7) * 132) + (t8 & 127);
        v8s uu = *(const v8s*)(urow + t8);
        v4f u0, u1;
#pragma unroll
        for (int j = 0; j < 4; ++j) {
            u0[j] = bf2f((ushort_t)uu[j]);
            u1[j] = bf2f((ushort_t)uu[4 + j]);
        }
        *(v4f*)&s_u[li]     = u0;
        *(v4f*)&s_u[li + 4] = u1;
        const float* dt0 = dtT + (size_t)b * 6 * LL + t8;
        const float* wr = dtw + d * 6;    // block-uniform -> scalar loads
        float w0 = wr[0], w1 = wr[1], w2 = wr[2], w3 = wr[3], w4 = wr[4], w5 = wr[5];
        float bb = dtpb[d];
        {
            v4f ra[6];
#pragma unroll
            for (int r = 0; r < 6; ++r) ra[r] = *(const v4f*)(dt0 + r * LL);
            v4f spa;
#pragma unroll
            for (int j = 0; j < 4; ++j) {
                float s1 = bb + w0 * ra[0][j] + w1 * ra[1][j] + w2 * ra[2][j]
                              + w3 * ra[3][j] + w4 * ra[4][j] + w5 * ra[5][j];
                spa[j] = 0.69314718f * flog2(1.f + fexp2(s1 * 1.44269504f));
            }
            *(v4f*)&s_d[li] = spa;
        }
        {
            v4f rb[6];
#pragma unroll
            for (int r = 0; r < 6; ++r) rb[r] = *(const v4f*)(dt0 + r * LL + 4);
            v4f spb;
#pragma unroll
            for (int j = 0; j < 4; ++j) {
                float s2 = bb + w0 * rb[0][j] + w1 * rb[1][j] + w2 * rb[2][j]
                              + w3 * rb[3][j] + w4 * rb[4][j] + w5 * rb[5][j];
                spb[j] = 0.69314718f * flog2(1.f + fexp2(s2 * 1.44269504f));
            }
            *(v4f*)&s_d[li + 4] = spb;
        }
    }
    __syncthreads();

    int t0 = cg * 128;
    int lb = cg * 132;
    const float* pB = BtP + ((size_t)b * LL + t0) * 16 + n;
    const float* pC = CtP + ((size_t)b * LL + t0) * 16 + n;

    // ---- phase 1: per-chunk aggregates; aP in log space
    float h = 0.f, sdu = 0.f;
    float4 du_c = *(float4*)&s_d[lb];
    float4 u_c  = *(float4*)&s_u[lb];
    float B0 = pB[0], B1 = pB[16], B2 = pB[32], B3 = pB[48];
    for (int s = 0; s < 31; ++s) {
        int ln = lb + s * 4 + 4;
        const float* pBn = pB + s * 64 + 64;
        float4 du_n = *(float4*)&s_d[ln];
        float4 u_n  = *(float4*)&s_u[ln];
        float Bn0 = pBn[0], Bn1 = pBn[16], Bn2 = pBn[32], Bn3 = pBn[48];
        float a0 = fexp2(du_c.x * A2), a1 = fexp2(du_c.y * A2);
        float a2 = fexp2(du_c.z * A2), a3 = fexp2(du_c.w * A2);
        h = fmaf(a0, h, (du_c.x * u_c.x) * B0);
        h = fmaf(a1, h, (du_c.y * u_c.y) * B1);
        h = fmaf(a2, h, (du_c.z * u_c.z) * B2);
        h = fmaf(a3, h, (du_c.w * u_c.w) * B3);
        sdu += (du_c.x + du_c.y) + (du_c.z + du_c.w);
        du_c = du_n; u_c = u_n; B0 = Bn0; B1 = Bn1; B2 = Bn2; B3 = Bn3;
    }
    {
        float a0 = fexp2(du_c.x * A2), a1 = fexp2(du_c.y * A2);
        float a2 = fexp2(du_c.z * A2), a3 = fexp2(du_c.w * A2);
        h = fmaf(a0, h, (du_c.x * u_c.x) * B0);
        h = fmaf(a1, h, (du_c.y * u_c.y) * B1);
        h = fmaf(a2, h, (du_c.z * u_c.z) * B2);
        h = fmaf(a3, h, (du_c.w * u_c.w) * B3);
        sdu += (du_c.x + du_c.y) + (du_c.z + du_c.w);
    }
    s_a[cg][n] = fexp2(sdu * A2);
    s_h[cg][n] = h;
    __syncthreads();

    // ---- phase 2: Kogge-Stone scan of 32 chunk aggregates (per n)
    {
        int l = tid & 63, w = tid >> 6;
        int c = l & 31, nn = (w << 1) | (l >> 5);
        float a  = s_a[c][nn];
        float hh = s_h[c][nn];
#pragma unroll
        for (int st = 1; st < 32; st <<= 1) {
            float ap = __shfl_up(a, st, 32);
            float hp = __shfl_up(hh, st, 32);
            bool ok = (c >= st);
            hh = ok ? fmaf(a, hp, hh) : hh;
            a  = ok ? a * ap : a;
        }
        float h0 = __shfl_up(hh, 1, 32);
        if (c == 0) h0 = 0.f;
        s_a[c][nn] = h0;
    }
    __syncthreads();

    // ---- phase 3: recompute with h0; 5-step select-exchange reduce; lane-t epilogue
    h = s_a[cg][n];
    const bool b0 = (n & 1), b1 = (n & 2);
    const int j = n & 3;
    const bool e1 = (j == 1), e2 = (j == 2), e3 = (j == 3);
    du_c = *(float4*)&s_d[lb];
    u_c  = *(float4*)&s_u[lb];
    B0 = pB[0]; B1 = pB[16]; B2 = pB[32]; B3 = pB[48];
    float C0 = pC[0], C1 = pC[16], C2 = pC[32], C3 = pC[48];
    ushort4 z_c = *(const ushort4*)(zrow + t0);
    for (int s = 0; s < 32; ++s) {
        float4 du_n, u_n;
        ushort4 z_n;
        float Bn0, Bn1, Bn2, Bn3, Cn0, Cn1, Cn2, Cn3;
        if (s < 31) {
            int ln = lb + s * 4 + 4;
            const float* pBn = pB + s * 64 + 64;
            const float* pCn = pC + s * 64 + 64;
            du_n = *(float4*)&s_d[ln];
            u_n  = *(float4*)&s_u[ln];
            Bn0 = pBn[0]; Bn1 = pBn[16]; Bn2 = pBn[32]; Bn3 = pBn[48];
            Cn0 = pCn[0]; Cn1 = pCn[16]; Cn2 = pCn[32]; Cn3 = pCn[48];
            z_n = *(const ushort4*)(zrow + t0 + s * 4 + 4);
        }
        float a0 = fexp2(du_c.x * A2), a1 = fexp2(du_c.y * A2);
        float a2 = fexp2(du_c.z * A2), a3 = fexp2(du_c.w * A2);
        h = fmaf(a0, h, (du_c.x * u_c.x) * B0); float p0 = h * C0;
        h = fmaf(a1, h, (du_c.y * u_c.y) * B1); float p1 = h * C1;
        h = fmaf(a2, h, (du_c.z * u_c.z) * B2); float p2 = h * C2;
        h = fmaf(a3, h, (du_c.w * u_c.w) * B3); float p3 = h * C3;
        // select-exchange tree: 5 shuffles total, lane n ends with sum_n p_{n&3}
        float xk = b0 ? p1 : p0;
        float xs = b0 ? p0 : p1;
        float yk = b0 ? p3 : p2;
        float ys = b0 ? p2 : p3;
        xk += __shfl_xor(xs, 1);
        yk += __shfl_xor(ys, 1);
        float vk = b1 ? yk : xk;
        float vs = b1 ? xk : yk;
        vk += __shfl_xor(vs, 2);
        vk += __shfl_xor(vk, 4);
        vk += __shfl_xor(vk, 8);
        float pj = vk;
        float uj = e3 ? u_c.w : (e2 ? u_c.z : (e1 ? u_c.y : u_c.x));
        ushort_t zu = e3 ? z_c.w : (e2 ? z_c.z : (e1 ? z_c.y : z_c.x));
        float yj = fmaf(Dd, uj, pj) * siluf(bf2f(zu));
        if (n < 4)
            ygr[t0 + s * 4 + n] = f2bf(yj);
        du_c = du_n; u_c = u_n; z_c = z_n;
        B0 = Bn0; B1 = Bn1; B2 = Bn2; B3 = Bn3;
        C0 = Cn0; C1 = Cn1; C2 = Cn2; C3 = Cn3;
    }
}

// ---------------- Kernel 5: out_proj via MFMA, 16-l blocks
__global__ __launch_bounds__(384, 6) void k_outproj(const ushort_t* __restrict__ xzb,
                                                    const ushort_t* __restrict__ Wobf,
                                                    float* __restrict__ out) {
    __shared__ ushort_t s_yg[16][232];
    int tid = threadIdx.x;
    int b = blockIdx.y;
    int l0 = blockIdx.x * 16;
    const ushort_t* ygb = xzb + (size_t)b * 384 * LL;
    if (tid < 96) {
        int q = tid >> 1, o = tid & 1;
        uint4 v[4];
#pragma unroll
        for (int jj = 0; jj < 4; ++jj)
            v[jj] = *(const uint4*)(ygb + (size_t)(q * 4 + jj) * LL + l0 + o * 8);
        const ushort_t* vs = (const ushort_t*)v;
#pragma unroll
        for (int j2 = 0; j2 < 8; ++j2) {
            ushort4 pk;
            pk.x = vs[j2]; pk.y = vs[8 + j2]; pk.z = vs[16 + j2]; pk.w = vs[24 + j2];
            *(ushort4*)&s_yg[o * 8 + j2][q * 4] = pk;
        }
    }
    __syncthreads();
    int w = tid >> 6, l = tid & 63;
    int n = l & 15, g = l >> 4;
    int c0 = w * 16;
    const ushort_t* bp = &s_yg[n][g * 8];
    const ushort_t* ap = Wobf + ((size_t)c0 + n) * 192 + g * 8;
    v4f acc = {0.f, 0.f, 0.f, 0.f};
#pragma unroll
    for (int kk = 0; kk < 6; ++kk) {
        v8s bf = *(const v8s*)(bp + kk * 32);
        v8s af = *(const v8s*)(ap + kk * 32);
        acc = __builtin_amdgcn_mfma_f32_16x16x32_bf16(af, bf, acc, 0, 0, 0);
    }
    float* ob = out + (size_t)b * 96 * LL + l0 + n;
#pragma unroll
    for (int r = 0; r < 4; ++r)
        ob[(size_t)(c0 + g * 4 + r) * LL] = acc[r];
}

extern "C" void kernel_launch(void* const* d_in, const int* in_sizes, int n_in,
                              void* d_out, int out_size, void* d_ws, size_t ws_size,
                              hipStream_t stream) {
    const float* x         = (const float*)d_in[0];
    const float* proj_w    = (const float*)d_in[1];
    const float* dconv_w   = (const float*)d_in[2];
    const float* in_proj_w = (const float*)d_in[3];
    const float* conv1d_w  = (const float*)d_in[4];
    const float* conv1d_b  = (const float*)d_in[5];
    const float* x_proj_w  = (const float*)d_in[6];
    const float* dt_proj_w = (const float*)d_in[7];
    const float* dt_proj_b = (const float*)d_in[8];
    const float* A_log     = (const float*)d_in[9];
    const float* Dp        = (const float*)d_in[10];
    const float* out_proj_w= (const float*)d_in[11];
    float* out = (float*)d_out;
    float* ws  = (float*)d_ws;

    // carve (float units)
    ushort_t* Wbf  = (ushort_t*)ws;                      // 82,944 sh -> 41,472 fl
    ushort_t* Wibf = (ushort_t*)(ws + 41472);            // 36,864 sh -> 18,432 fl
    ushort_t* Wobf = (ushort_t*)(ws + 59904);            // 18,432 sh ->  9,216 fl
    ushort_t* Wxbf = (ushort_t*)(ws + 69120);            //  9,216 sh ->  4,608 fl
    ushort_t* xT   = (ushort_t*)(ws + 73728);            // 1,723,392 sh -> 861,696 fl
    ushort_t* xzb  = (ushort_t*)(ws + 1721856);          // 4*384*4096 bf16 -> 3,145,728 fl
    float* dtT  = ws + 4867584;                          // 4*6*4096   =    98,304
    float* BtP  = dtT + 98304;                           // 4*4096*16  =   262,144
    float* CtP  = BtP + 262144;                          // 4*4096*16  =   262,144
    ushort_t* xcR = (ushort_t*)(CtP + 262144);           // 4*192*4096 bf16
    // yg[d][t] bf16 aliases xzb lower (xin) half per-batch (dead after convxp)

    k_prep<<<dim3(612), dim3(256), 0, stream>>>(proj_w, dconv_w, in_proj_w, out_proj_w,
                                                x_proj_w, x, Wbf, Wibf, Wobf, Wxbf, xT);
    k_convin<<<dim3(1024), dim3(384), 0, stream>>>(xT, Wbf, Wibf, xzb);
    k_convxp<<<dim3(128, 4), dim3(384), 0, stream>>>(xzb, conv1d_w, conv1d_b, Wxbf,
                                                     xcR, dtT, BtP, CtP);
    k_scan<<<dim3(768), dim3(512), 0, stream>>>(dtT, dt_proj_w, dt_proj_b, xcR, BtP, CtP,
                                                A_log, Dp, xzb);
    k_outproj<<<dim3(256, 4), dim3(384), 0, stream>>>(xzb, Wobf, out);
}

// Round 19
// 109.469 us; speedup vs baseline: 1.0669x; 1.0669x over previous
//
#include <hip/hip_runtime.h>
#include <math.h>

#define LL    4096
#define CDIM  96
#define DIN   192
#define NST   16
#define XE    38   // dt_rank(6) + 2*16

typedef __attribute__((ext_vector_type(8))) short v8s;
typedef __attribute__((ext_vector_type(4))) float v4f;
typedef unsigned short ushort_t;
typedef unsigned int uint_t;

#if __has_builtin(__builtin_amdgcn_exp2f)
__device__ __forceinline__ float fexp2(float x) { return __builtin_amdgcn_exp2f(x); }
#else
__device__ __forceinline__ float fexp2(float x) { return exp2f(x); }
#endif
#if __has_builtin(__builtin_amdgcn_logf)
__device__ __forceinline__ float flog2(float x) { return __builtin_amdgcn_logf(x); }
#else
__device__ __forceinline__ float flog2(float x) { return __log2f(x); }
#endif

__device__ __forceinline__ float siluf(float x) {
    return x * __builtin_amdgcn_rcpf(1.f + fexp2(-1.44269504f * x));
}
__device__ __forceinline__ ushort_t f2bf(float f) {
    uint_t u = __builtin_bit_cast(uint_t, f);
    return (ushort_t)((u + 0x7fffu + ((u >> 16) & 1u)) >> 16);
}
__device__ __forceinline__ float bf2f(ushort_t u) {
    return __builtin_bit_cast(float, (uint_t)u << 16);
}

// ---------------- Kernel 1: weight prep (LDS-staged merge) + cvt + x pad, ONE launch
__global__ __launch_bounds__(256) void k_prep(const float* __restrict__ proj_w,
                                              const float* __restrict__ dconv_w,
                                              const float* __restrict__ in_proj_w,
                                              const float* __restrict__ out_proj_w,
                                              const float* __restrict__ x_proj_w,
                                              const float* __restrict__ x,
                                              ushort_t* __restrict__ Wbf,
                                              ushort_t* __restrict__ Wibf,
                                              ushort_t* __restrict__ Wobf,
                                              ushort_t* __restrict__ Wxbf,
                                              ushort_t* __restrict__ xT) {
    __shared__ float s_dc[1728];
    int bid = blockIdx.x;
    if (bid < 96) {                       // merge proj into dconv, block per o
        int o = bid;
        for (int i = threadIdx.x; i < 1728; i += 256)
            s_dc[i] = dconv_w[o * 1728 + i];     // contiguous (i = j*9+k)
        __syncthreads();
        for (int u2 = threadIdx.x; u2 < 864; u2 += 256) {
            int c = u2 % 96, k = u2 / 96;
            float s = 0.f;
            for (int j2 = 0; j2 < 192; ++j2)
                s = fmaf(s_dc[j2 * 9 + k], proj_w[j2 * 96 + c], s);
            Wbf[(k * 96 + o) * 96 + c] = f2bf(s);
        }
        return;
    }
    if (bid < 348) {                      // weight cvt
        int i = (bid - 96) * 256 + threadIdx.x;
        if (i < 36864) { Wibf[i] = f2bf(in_proj_w[i]); return; }
        i -= 36864;
        if (i < 18432) { Wobf[i] = f2bf(out_proj_w[i]); return; }
        i -= 18432;
        if (i < 9216) {
            int e = i / 192;
            Wxbf[i] = (e < XE) ? f2bf(x_proj_w[i]) : (ushort_t)0;
        }
        return;
    }
    // xpad: x (B,96,64,64) f32 -> xT[b][66][68][96] bf16, zero halo
    int bid2 = bid - 348;
    int yy = bid2 % 66;
    int b  = bid2 / 66;
    int yv = yy - 1;
    for (int i = threadIdx.x; i < 68 * 12; i += 256) {
        int xx = i % 68, cig = i / 68;
        int xv = xx - 1;
        ushort_t u[8];
        if (yv >= 0 && yv < 64 && xv >= 0 && xv < 64) {
            const float* sp = x + ((size_t)(b * 96 + cig * 8)) * LL + yv * 64 + xv;
#pragma unroll
            for (int j = 0; j < 8; ++j) u[j] = f2bf(sp[j * LL]);
        } else {
#pragma unroll
            for (int j = 0; j < 8; ++j) u[j] = 0;
        }
        uint4 pk;
        pk.x = u[0] | ((uint_t)u[1] << 16); pk.y = u[2] | ((uint_t)u[3] << 16);
        pk.z = u[4] | ((uint_t)u[5] << 16); pk.w = u[6] | ((uint_t)u[7] << 16);
        *(uint4*)(xT + (((size_t)b * 66 + yy) * 68 + xx) * 96 + cig * 8) = pk;
    }
}

// ---------------- Kernel 2: FUSED 3x3-conv + in_proj via MFMA, LDS-staged input tile
__global__ __launch_bounds__(384, 2) void k_convin(const ushort_t* __restrict__ xT,
                                                   const ushort_t* __restrict__ Wbf,
                                                   const ushort_t* __restrict__ Wibf,
                                                   ushort_t* __restrict__ xzb) {
    __shared__ ushort_t s_xt[3 * 34 * 100];   // 20.4 KB
    __shared__ ushort_t s_seq[32 * 104];      // 6.5 KB
    int tid = threadIdx.x;
    int w = tid >> 6, l = tid & 63;
    int n = l & 15, g = l >> 4;
    int blk = blockIdx.x;
    int b = blk >> 7, rem = blk & 127;
    int y = rem >> 1, half = rem & 1;
    int lx = (w & 1) * 16;
    int co0 = (w >> 1) * 32;
    {
        const ushort_t* gsrc = xT + ((size_t)(b * 66 + y) * 68 + half * 32) * 96;
        for (int idx = tid; idx < 1224; idx += 384) {
            int r = idx / 408, rm = idx % 408;
            int col = rm / 12, ci8 = rm % 12;
            uint4 v = *(const uint4*)(gsrc + ((size_t)r * 68 + col) * 96 + ci8 * 8);
            *(uint4*)&s_xt[(r * 34 + col) * 100 + ci8 * 8] = v;
        }
    }
    __syncthreads();
    v4f acc0 = {0.f, 0.f, 0.f, 0.f};
    v4f acc1 = {0.f, 0.f, 0.f, 0.f};
    const ushort_t* xbl = &s_xt[(lx + n) * 100 + g * 8];
    const ushort_t* aw = Wbf + ((size_t)co0 + n) * 96 + g * 8;
#pragma unroll
    for (int tap = 0; tap < 9; ++tap) {
        int dy = tap / 3, dx = tap % 3;
        const ushort_t* bp = xbl + (dy * 34 + dx) * 100;
        const ushort_t* ap = aw + (size_t)tap * 9216;
#pragma unroll
        for (int kk = 0; kk < 3; ++kk) {
            v8s bf = *(const v8s*)(bp + kk * 32);
            v8s a0 = *(const v8s*)(ap + kk * 32);
            v8s a1 = *(const v8s*)(ap + 1536 + kk * 32);
            acc0 = __builtin_amdgcn_mfma_f32_16x16x32_bf16(a0, bf, acc0, 0, 0, 0);
            acc1 = __builtin_amdgcn_mfma_f32_16x16x32_bf16(a1, bf, acc1, 0, 0, 0);
        }
    }
    {
        int ll = lx + n;
        ushort_t* sp = s_seq + ll * 104 + co0 + g * 4;
        ushort4 p0, p1;
        p0.x = f2bf(acc0[0]); p0.y = f2bf(acc0[1]); p0.z = f2bf(acc0[2]); p0.w = f2bf(acc0[3]);
        p1.x = f2bf(acc1[0]); p1.y = f2bf(acc1[1]); p1.z = f2bf(acc1[2]); p1.w = f2bf(acc1[3]);
        *(ushort4*)sp = p0;
        *(ushort4*)(sp + 16) = p1;
    }
    __syncthreads();
    int coh = w * 64;
    v4f acc[4][2];
#pragma unroll
    for (int mt = 0; mt < 4; ++mt)
#pragma unroll
        for (int lt = 0; lt < 2; ++lt) acc[mt][lt] = (v4f){0.f, 0.f, 0.f, 0.f};
    const ushort_t* ap2 = Wibf + ((size_t)coh + n) * 96 + g * 8;
#pragma unroll
    for (int lt = 0; lt < 2; ++lt) {
        const ushort_t* bp2 = s_seq + (lt * 16 + n) * 104 + g * 8;
#pragma unroll
        for (int kk = 0; kk < 3; ++kk) {
            v8s bf = *(const v8s*)(bp2 + kk * 32);
#pragma unroll
            for (int mt = 0; mt < 4; ++mt) {
                v8s af = *(const v8s*)(ap2 + mt * 16 * 96 + kk * 32);
                acc[mt][lt] = __builtin_amdgcn_mfma_f32_16x16x32_bf16(af, bf, acc[mt][lt], 0, 0, 0);
            }
        }
    }
    int l0g = y * 64 + half * 32;
    ushort_t* ob = xzb + (size_t)b * 384 * LL + l0g + n;
#pragma unroll
    for (int mt = 0; mt < 4; ++mt) {
        int e = coh + mt * 16 + g * 4;
#pragma unroll
        for (int lt = 0; lt < 2; ++lt)
#pragma unroll
            for (int r = 0; r < 4; ++r)
                ob[(size_t)(e + r) * LL + lt * 16] = f2bf(acc[mt][lt][r]);
    }
}

// ---------------- Kernel 3: FUSED conv1d+SiLU + x_proj, 6 balanced MFMA waves
__global__ __launch_bounds__(384, 2) void k_convxp(const ushort_t* __restrict__ xzb,
                                                   const float* __restrict__ c1w,
                                                   const float* __restrict__ c1b,
                                                   const ushort_t* __restrict__ Wxbf,
                                                   ushort_t* __restrict__ xcR,
                                                   float* __restrict__ dtT,
                                                   float* __restrict__ BtP,
                                                   float* __restrict__ CtP) {
    __shared__ ushort_t s_xc[32][200];
    int tid = threadIdx.x;
    int b = blockIdx.y;
    int l0 = blockIdx.x * 32;
    if (tid < 192) {
        int d = tid;
        const ushort_t* xin = xzb + (size_t)(b * 384 + d) * LL;
        float e[35];
        if (l0 > 0) {
            v8s pv = *(const v8s*)(xin + l0 - 8);
            e[0] = bf2f((ushort_t)pv[5]); e[1] = bf2f((ushort_t)pv[6]); e[2] = bf2f((ushort_t)pv[7]);
        } else {
            e[0] = e[1] = e[2] = 0.f;
        }
#pragma unroll
        for (int q = 0; q < 4; ++q) {
            v8s cv = *(const v8s*)(xin + l0 + q * 8);
#pragma unroll
            for (int j = 0; j < 8; ++j) e[3 + q * 8 + j] = bf2f((ushort_t)cv[j]);
        }
        float w0 = c1w[d * 4], w1 = c1w[d * 4 + 1], w2 = c1w[d * 4 + 2], w3 = c1w[d * 4 + 3];
        float bb = c1b[d];
        ushort_t* xr = xcR + (size_t)(b * 192 + d) * LL + l0;
#pragma unroll
        for (int q = 0; q < 4; ++q) {
            v8s ov;
#pragma unroll
            for (int j = 0; j < 8; ++j) {
                int i = q * 8 + j;
                float s = bb + w0 * e[i] + w1 * e[i + 1] + w2 * e[i + 2] + w3 * e[i + 3];
                ushort_t uv = f2bf(siluf(s));
                ov[j] = (short)uv;
                s_xc[i][d] = uv;
            }
            *(v8s*)(xr + q * 8) = ov;
        }
    }
    __syncthreads();
    // 6 waves: wave w -> (t-half th = w&1, m-tile m = w>>1); 6 MFMAs each
    int w = tid >> 6, l = tid & 63;
    int n = l & 15, g = l >> 4;
    int th = w & 1, m = w >> 1;
    int lt = th * 16;
    int t = l0 + lt + n;
    const ushort_t* ap = Wxbf + ((size_t)(m * 16) + n) * 192 + g * 8;
    float* dtb = dtT + (size_t)b * 6 * LL + t;
    float* Bb  = BtP + ((size_t)b * LL + t) * 16;
    float* Cb  = CtP + ((size_t)b * LL + t) * 16;
    v4f acc = {0.f, 0.f, 0.f, 0.f};
#pragma unroll
    for (int kk = 0; kk < 6; ++kk) {
        v8s bf = *(const v8s*)&s_xc[lt + n][g * 8 + kk * 32];
        v8s af = *(const v8s*)(ap + kk * 32);
        acc = __builtin_amdgcn_mfma_f32_16x16x32_bf16(af, bf, acc, 0, 0, 0);
    }
#pragma unroll
    for (int r = 0; r < 4; ++r) {
        int e = m * 16 + g * 4 + r;
        float v = acc[r];
        if (e < 6)       dtb[(size_t)e * LL] = v;
        else if (e < 22) Bb[e - 6] = v;
        else if (e < 38) Cb[e - 22] = v;
    }
}

// ---------------- Kernel 4: selective scan (fused dt_proj+softplus) -> yg[d][t] bf16
__global__ __launch_bounds__(512, 6) void k_scan(const float* __restrict__ dtT,
                                                 const float* __restrict__ dtw,
                                                 const float* __restrict__ dtpb,
                                                 const ushort_t* __restrict__ xcR,
                                                 const float* __restrict__ BtP,
                                                 const float* __restrict__ CtP,
                                                 const float* __restrict__ A_log,
                                                 const float* __restrict__ Dp,
                                                 ushort_t* __restrict__ xzb) {
    __shared__ float s_d[32 * 132];       // chunk c at c*132 (+4 pad)
    __shared__ float s_u[32 * 132];
    __shared__ float s_a[32][17];
    __shared__ float s_h[32][17];
    int tid = threadIdx.x;
    int n = tid & 15, cg = tid >> 4;      // 32 chunks x 16 states
    int bd = blockIdx.x;
    int d = bd % DIN, b = bd / DIN;
    const ushort_t* urow = xcR + (size_t)(b * 192 + d) * LL;
    const ushort_t* zrow = xzb + (size_t)(b * 384 + DIN + d) * LL;
    ushort_t* ygr = xzb + (size_t)(b * 384 + d) * LL;    // overwrites dead xin row
    float A2 = -__expf(A_log[d * NST + n]) * 1.44269504f;   // for fexp2
    float Dd = Dp[d];

    // ---- staging: u from xcR bf16; delta = softplus(dt_proj) in-kernel
    {
        int t8 = tid * 8;
        int li = ((t8 >> 7) * 132) + (t8 & 127);
        v8s uu = *(const v8s*)(urow + t8);
        v4f u0, u1;
#pragma unroll
        for (int j = 0; j < 4; ++j) {
            u0[j] = bf2f((ushort_t)uu[j]);
            u1[j] = bf2f((ushort_t)uu[4 + j]);
        }
        *(v4f*)&s_u[li]     = u0;
        *(v4f*)&s_u[li + 4] = u1;
        const float* dt0 = dtT + (size_t)b * 6 * LL + t8;
        const float* wr = dtw + d * 6;    // block-uniform -> scalar loads
        float w0 = wr[0], w1 = wr[1], w2 = wr[2], w3 = wr[3], w4 = wr[4], w5 = wr[5];
        float bb = dtpb[d];
        {
            v4f ra[6];
#pragma unroll
            for (int r = 0; r < 6; ++r) ra[r] = *(const v4f*)(dt0 + r * LL);
            v4f spa;
#pragma unroll
            for (int j = 0; j < 4; ++j) {
                float s1 = bb + w0 * ra[0][j] + w1 * ra[1][j] + w2 * ra[2][j]
                              + w3 * ra[3][j] + w4 * ra[4][j] + w5 * ra[5][j];
                spa[j] = 0.69314718f * flog2(1.f + fexp2(s1 * 1.44269504f));
            }
            *(v4f*)&s_d[li] = spa;
        }
        {
            v4f rb[6];
#pragma unroll
            for (int r = 0; r < 6; ++r) rb[r] = *(const v4f*)(dt0 + r * LL + 4);
            v4f spb;
#pragma unroll
            for (int j = 0; j < 4; ++j) {
                float s2 = bb + w0 * rb[0][j] + w1 * rb[1][j] + w2 * rb[2][j]
                              + w3 * rb[3][j] + w4 * rb[4][j] + w5 * rb[5][j];
                spb[j] = 0.69314718f * flog2(1.f + fexp2(s2 * 1.44269504f));
            }
            *(v4f*)&s_d[li + 4] = spb;
        }
    }
    __syncthreads();

    int t0 = cg * 128;
    int lb = cg * 132;
    const float* pB = BtP + ((size_t)b * LL + t0) * 16 + n;
    const float* pC = CtP + ((size_t)b * LL + t0) * 16 + n;

    // ---- phase 1: per-chunk aggregates; aP in log space
    float h = 0.f, sdu = 0.f;
    float4 du_c = *(float4*)&s_d[lb];
    float4 u_c  = *(float4*)&s_u[lb];
    float B0 = pB[0], B1 = pB[16], B2 = pB[32], B3 = pB[48];
    for (int s = 0; s < 31; ++s) {
        int ln = lb + s * 4 + 4;
        const float* pBn = pB + s * 64 + 64;
        float4 du_n = *(float4*)&s_d[ln];
        float4 u_n  = *(float4*)&s_u[ln];
        float Bn0 = pBn[0], Bn1 = pBn[16], Bn2 = pBn[32], Bn3 = pBn[48];
        float a0 = fexp2(du_c.x * A2), a1 = fexp2(du_c.y * A2);
        float a2 = fexp2(du_c.z * A2), a3 = fexp2(du_c.w * A2);
        h = fmaf(a0, h, (du_c.x * u_c.x) * B0);
        h = fmaf(a1, h, (du_c.y * u_c.y) * B1);
        h = fmaf(a2, h, (du_c.z * u_c.z) * B2);
        h = fmaf(a3, h, (du_c.w * u_c.w) * B3);
        sdu += (du_c.x + du_c.y) + (du_c.z + du_c.w);
        du_c = du_n; u_c = u_n; B0 = Bn0; B1 = Bn1; B2 = Bn2; B3 = Bn3;
    }
    {
        float a0 = fexp2(du_c.x * A2), a1 = fexp2(du_c.y * A2);
        float a2 = fexp2(du_c.z * A2), a3 = fexp2(du_c.w * A2);
        h = fmaf(a0, h, (du_c.x * u_c.x) * B0);
        h = fmaf(a1, h, (du_c.y * u_c.y) * B1);
        h = fmaf(a2, h, (du_c.z * u_c.z) * B2);
        h = fmaf(a3, h, (du_c.w * u_c.w) * B3);
        sdu += (du_c.x + du_c.y) + (du_c.z + du_c.w);
    }
    s_a[cg][n] = fexp2(sdu * A2);
    s_h[cg][n] = h;
    __syncthreads();

    // ---- phase 2: Kogge-Stone scan of 32 chunk aggregates (per n)
    {
        int l = tid & 63, w = tid >> 6;
        int c = l & 31, nn = (w << 1) | (l >> 5);
        float a  = s_a[c][nn];
        float hh = s_h[c][nn];
#pragma unroll
        for (int st = 1; st < 32; st <<= 1) {
            float ap = __shfl_up(a, st, 32);
            float hp = __shfl_up(hh, st, 32);
            bool ok = (c >= st);
            hh = ok ? fmaf(a, hp, hh) : hh;
            a  = ok ? a * ap : a;
        }
        float h0 = __shfl_up(hh, 1, 32);
        if (c == 0) h0 = 0.f;
        s_a[c][nn] = h0;
    }
    __syncthreads();

    // ---- phase 3: recompute with h0; 5-step select-exchange reduce; lane-t epilogue
    h = s_a[cg][n];
    const bool b0 = (n & 1), b1 = (n & 2);
    const int j = n & 3;
    const bool e1 = (j == 1), e2 = (j == 2), e3 = (j == 3);
    du_c = *(float4*)&s_d[lb];
    u_c  = *(float4*)&s_u[lb];
    B0 = pB[0]; B1 = pB[16]; B2 = pB[32]; B3 = pB[48];
    float C0 = pC[0], C1 = pC[16], C2 = pC[32], C3 = pC[48];
    ushort4 z_c = *(const ushort4*)(zrow + t0);
    for (int s = 0; s < 32; ++s) {
        float4 du_n, u_n;
        ushort4 z_n;
        float Bn0, Bn1, Bn2, Bn3, Cn0, Cn1, Cn2, Cn3;
        if (s < 31) {
            int ln = lb + s * 4 + 4;
            const float* pBn = pB + s * 64 + 64;
            const float* pCn = pC + s * 64 + 64;
            du_n = *(float4*)&s_d[ln];
            u_n  = *(float4*)&s_u[ln];
            Bn0 = pBn[0]; Bn1 = pBn[16]; Bn2 = pBn[32]; Bn3 = pBn[48];
            Cn0 = pCn[0]; Cn1 = pCn[16]; Cn2 = pCn[32]; Cn3 = pCn[48];
            z_n = *(const ushort4*)(zrow + t0 + s * 4 + 4);
        }
        float a0 = fexp2(du_c.x * A2), a1 = fexp2(du_c.y * A2);
        float a2 = fexp2(du_c.z * A2), a3 = fexp2(du_c.w * A2);
        h = fmaf(a0, h, (du_c.x * u_c.x) * B0); float p0 = h * C0;
        h = fmaf(a1, h, (du_c.y * u_c.y) * B1); float p1 = h * C1;
        h = fmaf(a2, h, (du_c.z * u_c.z) * B2); float p2 = h * C2;
        h = fmaf(a3, h, (du_c.w * u_c.w) * B3); float p3 = h * C3;
        // select-exchange tree: 5 shuffles total, lane n ends with sum_n p_{n&3}
        float xk = b0 ? p1 : p0;
        float xs = b0 ? p0 : p1;
        float yk = b0 ? p3 : p2;
        float ys = b0 ? p2 : p3;
        xk += __shfl_xor(xs, 1);
        yk += __shfl_xor(ys, 1);
        float vk = b1 ? yk : xk;
        float vs = b1 ? xk : yk;
        vk += __shfl_xor(vs, 2);
        vk += __shfl_xor(vk, 4);
        vk += __shfl_xor(vk, 8);
        float pj = vk;
        float uj = e3 ? u_c.w : (e2 ? u_c.z : (e1 ? u_c.y : u_c.x));
        ushort_t zu = e3 ? z_c.w : (e2 ? z_c.z : (e1 ? z_c.y : z_c.x));
        float yj = fmaf(Dd, uj, pj) * siluf(bf2f(zu));
        if (n < 4)
            ygr[t0 + s * 4 + n] = f2bf(yj);
        du_c = du_n; u_c = u_n; z_c = z_n;
        B0 = Bn0; B1 = Bn1; B2 = Bn2; B3 = Bn3;
        C0 = Cn0; C1 = Cn1; C2 = Cn2; C3 = Cn3;
    }
}

// ---------------- Kernel 5: out_proj via MFMA, 16-l blocks
__global__ __launch_bounds__(384, 6) void k_outproj(const ushort_t* __restrict__ xzb,
                                                    const ushort_t* __restrict__ Wobf,
                                                    float* __restrict__ out) {
    __shared__ ushort_t s_yg[16][232];
    int tid = threadIdx.x;
    int b = blockIdx.y;
    int l0 = blockIdx.x * 16;
    const ushort_t* ygb = xzb + (size_t)b * 384 * LL;
    if (tid < 96) {
        int q = tid >> 1, o = tid & 1;
        uint4 v[4];
#pragma unroll
        for (int jj = 0; jj < 4; ++jj)
            v[jj] = *(const uint4*)(ygb + (size_t)(q * 4 + jj) * LL + l0 + o * 8);
        const ushort_t* vs = (const ushort_t*)v;
#pragma unroll
        for (int j2 = 0; j2 < 8; ++j2) {
            ushort4 pk;
            pk.x = vs[j2]; pk.y = vs[8 + j2]; pk.z = vs[16 + j2]; pk.w = vs[24 + j2];
            *(ushort4*)&s_yg[o * 8 + j2][q * 4] = pk;
        }
    }
    __syncthreads();
    int w = tid >> 6, l = tid & 63;
    int n = l & 15, g = l >> 4;
    int c0 = w * 16;
    const ushort_t* bp = &s_yg[n][g * 8];
    const ushort_t* ap = Wobf + ((size_t)c0 + n) * 192 + g * 8;
    v4f acc = {0.f, 0.f, 0.f, 0.f};
#pragma unroll
    for (int kk = 0; kk < 6; ++kk) {
        v8s bf = *(const v8s*)(bp + kk * 32);
        v8s af = *(const v8s*)(ap + kk * 32);
        acc = __builtin_amdgcn_mfma_f32_16x16x32_bf16(af, bf, acc, 0, 0, 0);
    }
    float* ob = out + (size_t)b * 96 * LL + l0 + n;
#pragma unroll
    for (int r = 0; r < 4; ++r)
        ob[(size_t)(c0 + g * 4 + r) * LL] = acc[r];
}

extern "C" void kernel_launch(void* const* d_in, const int* in_sizes, int n_in,
                              void* d_out, int out_size, void* d_ws, size_t ws_size,
                              hipStream_t stream) {
    const float* x         = (const float*)d_in[0];
    const float* proj_w    = (const float*)d_in[1];
    const float* dconv_w   = (const float*)d_in[2];
    const float* in_proj_w = (const float*)d_in[3];
    const float* conv1d_w  = (const float*)d_in[4];
    const float* conv1d_b  = (const float*)d_in[5];
    const float* x_proj_w  = (const float*)d_in[6];
    const float* dt_proj_w = (const float*)d_in[7];
    const float* dt_proj_b = (const float*)d_in[8];
    const float* A_log     = (const float*)d_in[9];
    const float* Dp        = (const float*)d_in[10];
    const float* out_proj_w= (const float*)d_in[11];
    float* out = (float*)d_out;
    float* ws  = (float*)d_ws;

    // carve (float units)
    ushort_t* Wbf  = (ushort_t*)ws;                      // 82,944 sh -> 41,472 fl
    ushort_t* Wibf = (ushort_t*)(ws + 41472);            // 36,864 sh -> 18,432 fl
    ushort_t* Wobf = (ushort_t*)(ws + 59904);            // 18,432 sh ->  9,216 fl
    ushort_t* Wxbf = (ushort_t*)(ws + 69120);            //  9,216 sh ->  4,608 fl
    ushort_t* xT   = (ushort_t*)(ws + 73728);            // 1,723,392 sh -> 861,696 fl
    ushort_t* xzb  = (ushort_t*)(ws + 1721856);          // 4*384*4096 bf16 -> 3,145,728 fl
    float* dtT  = ws + 4867584;                          // 4*6*4096   =    98,304
    float* BtP  = dtT + 98304;                           // 4*4096*16  =   262,144
    float* CtP  = BtP + 262144;                          // 4*4096*16  =   262,144
    ushort_t* xcR = (ushort_t*)(CtP + 262144);           // 4*192*4096 bf16
    // yg[d][t] bf16 aliases xzb lower (xin) half per-batch (dead after convxp)

    k_prep<<<dim3(612), dim3(256), 0, stream>>>(proj_w, dconv_w, in_proj_w, out_proj_w,
                                                x_proj_w, x, Wbf, Wibf, Wobf, Wxbf, xT);
    k_convin<<<dim3(512), dim3(384), 0, stream>>>(xT, Wbf, Wibf, xzb);
    k_convxp<<<dim3(128, 4), dim3(384), 0, stream>>>(xzb, conv1d_w, conv1d_b, Wxbf,
                                                     xcR, dtT, BtP, CtP);
    k_scan<<<dim3(768), dim3(512), 0, stream>>>(dtT, dt_proj_w, dt_proj_b, xcR, BtP, CtP,
                                                A_log, Dp, xzb);
    k_outproj<<<dim3(256, 4), dim3(384), 0, stream>>>(xzb, Wobf, out);
}